// Round 1
// baseline (134.997 us; speedup 1.0000x reference)
//
#include <hip/hip_runtime.h>
#include <math.h>

#define MAX_SHIFT 128
#define S_TOTAL   (2 * MAX_SHIFT + 1)   // 257
#define TY        4096                   // time-chunk per block in cross kernel
#define SG        32                     // shifts per block
#define XTILE     (TY + 288)             // covers shift offsets up to 287 (last padded group)

// ---------------- Kernel 1: per-(b,c) global sums ----------------
__global__ __launch_bounds__(256) void sums_kernel(const float* __restrict__ x,
                                                   const float* __restrict__ y,
                                                   float* __restrict__ ws_sums, int T) {
    int bc = blockIdx.x;
    const float* xb = x + (size_t)bc * T;
    const float* yb = y + (size_t)bc * T;
    float sx = 0.f, sxx = 0.f, sy = 0.f, syy = 0.f;
    for (int t = threadIdx.x; t < T; t += 256) {
        float xv = xb[t], yv = yb[t];
        sx += xv; sxx += xv * xv;
        sy += yv; syy += yv * yv;
    }
    __shared__ float red[4][256];
    red[0][threadIdx.x] = sx;  red[1][threadIdx.x] = sxx;
    red[2][threadIdx.x] = sy;  red[3][threadIdx.x] = syy;
    __syncthreads();
    for (int off = 128; off > 0; off >>= 1) {
        if ((int)threadIdx.x < off) {
            red[0][threadIdx.x] += red[0][threadIdx.x + off];
            red[1][threadIdx.x] += red[1][threadIdx.x + off];
            red[2][threadIdx.x] += red[2][threadIdx.x + off];
            red[3][threadIdx.x] += red[3][threadIdx.x + off];
        }
        __syncthreads();
    }
    if (threadIdx.x == 0) {
        ws_sums[bc * 4 + 0] = red[0][0];
        ws_sums[bc * 4 + 1] = red[1][0];
        ws_sums[bc * 4 + 2] = red[2][0];
        ws_sums[bc * 4 + 3] = red[3][0];
    }
}

// ---------------- Kernel 2: cross-correlation ----------------
// grid: (T/TY, ceil(S/SG), BC), block 256
__global__ __launch_bounds__(256) void cross_kernel(const float* __restrict__ x,
                                                    const float* __restrict__ y,
                                                    float* __restrict__ cross,
                                                    int T, int BC) {
    const int tchunk = blockIdx.x;
    const int s0     = blockIdx.y * SG;
    const int bc     = blockIdx.z;
    const int t0     = tchunk * TY;
    const float* xb = x + (size_t)bc * T;
    const float* yb = y + (size_t)bc * T;

    __shared__ float xs[XTILE];
    // stage x tile covering global [t0 - MAX_SHIFT, t0 - MAX_SHIFT + XTILE)
    for (int k = threadIdx.x; k < XTILE; k += 256) {
        int g = t0 - MAX_SHIFT + k;
        xs[k] = (g >= 0 && g < T) ? xb[g] : 0.f;
    }
    __syncthreads();

    // y values for this chunk live in registers
    float yreg[TY / 256];
#pragma unroll
    for (int k = 0; k < TY / 256; ++k)
        yreg[k] = yb[t0 + k * 256 + threadIdx.x];

    float acc[SG];
#pragma unroll
    for (int j = 0; j < SG; ++j) acc[j] = 0.f;

    for (int k = 0; k < TY / 256; ++k) {
        const int base = k * 256 + threadIdx.x;   // t offset within chunk
        const float yv = yreg[k];
#pragma unroll
        for (int j = 0; j < SG; ++j) {
            // shift s = s0 + j, d = s - MAX_SHIFT; LDS x index = base + d + MAX_SHIFT = base + s
            acc[j] += xs[base + s0 + j] * yv;
        }
    }

    // wave-level reduction + atomic accumulation
    const int lane = threadIdx.x & 63;
    for (int j = 0; j < SG; ++j) {
        int s = s0 + j;
        float v = acc[j];
        for (int off = 32; off > 0; off >>= 1)
            v += __shfl_down(v, off, 64);
        if (lane == 0 && s < S_TOTAL)
            atomicAdd(&cross[(size_t)s * BC + bc], v);
    }
}

// ---------------- Kernel 3: finalize ----------------
__global__ __launch_bounds__(256) void finalize_kernel(const float* __restrict__ x,
                                                       const float* __restrict__ ws_sums,
                                                       const float* __restrict__ cross,
                                                       float* __restrict__ out,
                                                       int T, int BC) {
    int idx = blockIdx.x * blockDim.x + threadIdx.x;
    if (idx >= S_TOTAL * BC) return;
    int s  = idx / BC;
    int bc = idx - s * BC;
    int d  = s - MAX_SHIFT;
    const float* xb = x + (size_t)bc * T;

    float Sx  = ws_sums[bc * 4 + 0];
    float Sxx = ws_sums[bc * 4 + 1];
    float Sy  = ws_sums[bc * 4 + 2];
    float Syy = ws_sums[bc * 4 + 3];

    // edge corrections: remove elements of x that fall outside the valid window
    float pw = 0.f, pw2 = 0.f;
    if (d > 0) {
        for (int j = 0; j < d; ++j) { float v = xb[j]; pw += v; pw2 += v * v; }
    } else if (d < 0) {
        for (int j = T + d; j < T; ++j) { float v = xb[j]; pw += v; pw2 += v * v; }
    }
    float sum_w  = Sx  - pw;
    float sum_w2 = Sxx - pw2;

    float cr    = cross[idx];
    float invT  = 1.0f / (float)T;
    float corr  = cr - sum_w * Sy * invT;
    float normx = sum_w2 - sum_w * sum_w * invT;
    float normy = Syy - Sy * Sy * invT;
    out[idx] = corr / sqrtf(normx * normy);
}

extern "C" void kernel_launch(void* const* d_in, const int* in_sizes, int n_in,
                              void* d_out, int out_size, void* d_ws, size_t ws_size,
                              hipStream_t stream) {
    const float* x = (const float*)d_in[0];
    const float* y = (const float*)d_in[1];
    float* out = (float*)d_out;

    const int S  = S_TOTAL;                 // max_shift = 128 (fixed by setup_inputs)
    const int BC = out_size / S;            // 8
    const int T  = in_sizes[0] / BC;        // 32768

    float* ws_sums = (float*)d_ws;          // BC*4 floats
    float* cross   = ws_sums + BC * 4;      // S*BC floats

    hipMemsetAsync(cross, 0, sizeof(float) * (size_t)S * BC, stream);

    sums_kernel<<<BC, 256, 0, stream>>>(x, y, ws_sums, T);

    dim3 grid_c(T / TY, (S + SG - 1) / SG, BC);
    cross_kernel<<<grid_c, 256, 0, stream>>>(x, y, cross, T, BC);

    int tot = S * BC;
    finalize_kernel<<<(tot + 255) / 256, 256, 0, stream>>>(x, ws_sums, cross, out, T, BC);
}

// Round 2
// 88.667 us; speedup vs baseline: 1.5225x; 1.5225x over previous
//
#include <hip/hip_runtime.h>
#include <math.h>

#define MAX_SHIFT 128
#define S_TOTAL   (2 * MAX_SHIFT + 1)   // 257
#define TY        4096                   // time-chunk per block in cross kernel
#define SG        32                     // shifts per block
#define NSG       9                      // ceil(257/32) -> covers s in [0,288)
#define S_PAD     (NSG * SG)             // 288
#define XTILE     (TY + S_PAD)           // 4384 floats, 17.5 KB
#define KBLK      (TY / 1024)            // 4 k-iterations (each thread does 4 consecutive t x 4 iters)

// ---------------- Kernel 1: cross-correlation + fused sums ----------------
// grid: (T/TY, NSG, BC), block 256.
// Writes cross partials to ws_cross[(s*NCH + chunk)*BC + bc] (s in [0,288)).
// blockIdx.y==0 blocks also write sums partials ws_sums[(bc*NCH + chunk)*4 + {0..3}].
__global__ __launch_bounds__(256) void cross_kernel(const float* __restrict__ x,
                                                    const float* __restrict__ y,
                                                    float* __restrict__ ws_cross,
                                                    float* __restrict__ ws_sums,
                                                    int T, int BC, int NCH) {
    const int chunk = blockIdx.x;
    const int s0    = blockIdx.y * SG;
    const int bc    = blockIdx.z;
    const int t0    = chunk * TY;
    const int tid   = threadIdx.x;
    const float* xb = x + (size_t)bc * T;
    const float* yb = y + (size_t)bc * T;

    __shared__ __align__(16) float xs[XTILE];

    // ---- stage x tile: global [t0-128, t0-128+XTILE) -> xs[0..XTILE) ----
    for (int l = tid * 4; l < XTILE; l += 256 * 4) {
        int g = t0 - MAX_SHIFT + l;
        float4 v;
        if (g >= 0 && g + 3 < T) {
            v = *(const float4*)(xb + g);
        } else {
            float* pv = (float*)&v;
            for (int e = 0; e < 4; ++e) {
                int gg = g + e;
                pv[e] = (gg >= 0 && gg < T) ? xb[gg] : 0.f;
            }
        }
        *(float4*)(xs + l) = v;
    }
    __syncthreads();

    float acc[SG];
#pragma unroll
    for (int j = 0; j < SG; ++j) acc[j] = 0.f;

    const bool do_sums = (blockIdx.y == 0);
    float sx = 0.f, sxx = 0.f, sy = 0.f, syy = 0.f;

#pragma unroll
    for (int k = 0; k < KBLK; ++k) {
        const int base = k * 1024 + tid * 4;              // t offset within chunk, 16B aligned
        const float4 y4 = *(const float4*)(yb + t0 + base);

        // x window: LDS indices [base+s0, base+s0+36), 9 aligned b128 reads
        float xw[36];
#pragma unroll
        for (int i = 0; i < 9; ++i)
            *(float4*)(xw + 4 * i) = *(const float4*)(xs + base + s0 + 4 * i);

#pragma unroll
        for (int j = 0; j < SG; ++j) {
            acc[j] = fmaf(xw[j + 0], y4.x,
                     fmaf(xw[j + 1], y4.y,
                     fmaf(xw[j + 2], y4.z,
                     fmaf(xw[j + 3], y4.w, acc[j]))));
        }

        if (do_sums) {
            const float4 x4 = *(const float4*)(xs + MAX_SHIFT + base);
            sy  += y4.x + y4.y + y4.z + y4.w;
            syy += y4.x * y4.x + y4.y * y4.y + y4.z * y4.z + y4.w * y4.w;
            sx  += x4.x + x4.y + x4.z + x4.w;
            sxx += x4.x * x4.x + x4.y * x4.y + x4.z * x4.z + x4.w * x4.w;
        }
    }

    // ---- block reduction of acc[j]: wave shuffle -> LDS -> 4-way sum ----
    __shared__ float red[SG][4];
    const int lane = tid & 63;
    const int wave = tid >> 6;
#pragma unroll
    for (int j = 0; j < SG; ++j) {
        float v = acc[j];
        for (int off = 32; off > 0; off >>= 1)
            v += __shfl_down(v, off, 64);
        if (lane == 0) red[j][wave] = v;
    }
    __syncthreads();
    if (tid < SG) {
        float v = red[tid][0] + red[tid][1] + red[tid][2] + red[tid][3];
        int s = s0 + tid;
        ws_cross[((size_t)s * NCH + chunk) * BC + bc] = v;
    }

    // ---- block reduction of sums (only y==0 blocks) ----
    if (do_sums) {
        __shared__ float sred[4][4];   // [quantity][wave]
        float vals[4] = {sx, sxx, sy, syy};
#pragma unroll
        for (int q = 0; q < 4; ++q) {
            float v = vals[q];
            for (int off = 32; off > 0; off >>= 1)
                v += __shfl_down(v, off, 64);
            if (lane == 0) sred[q][wave] = v;
        }
        __syncthreads();
        if (tid < 4) {
            float v = sred[tid][0] + sred[tid][1] + sred[tid][2] + sred[tid][3];
            ws_sums[((size_t)bc * NCH + chunk) * 4 + tid] = v;
        }
    }
}

// ---------------- Kernel 2: finalize ----------------
__global__ __launch_bounds__(256) void finalize_kernel(const float* __restrict__ x,
                                                       const float* __restrict__ ws_cross,
                                                       const float* __restrict__ ws_sums,
                                                       float* __restrict__ out,
                                                       int T, int BC, int NCH) {
    int idx = blockIdx.x * blockDim.x + threadIdx.x;
    if (idx >= S_TOTAL * BC) return;
    int s  = idx / BC;
    int bc = idx - s * BC;
    int d  = s - MAX_SHIFT;
    const float* xb = x + (size_t)bc * T;

    float Sx = 0.f, Sxx = 0.f, Sy = 0.f, Syy = 0.f;
    for (int c = 0; c < NCH; ++c) {
        Sx  += ws_sums[((size_t)bc * NCH + c) * 4 + 0];
        Sxx += ws_sums[((size_t)bc * NCH + c) * 4 + 1];
        Sy  += ws_sums[((size_t)bc * NCH + c) * 4 + 2];
        Syy += ws_sums[((size_t)bc * NCH + c) * 4 + 3];
    }

    float cr = 0.f;
    for (int c = 0; c < NCH; ++c)
        cr += ws_cross[((size_t)s * NCH + c) * BC + bc];

    // edge corrections: remove x elements falling outside the valid window
    float pw = 0.f, pw2 = 0.f;
    if (d > 0) {
        for (int j = 0; j < d; ++j) { float v = xb[j]; pw += v; pw2 += v * v; }
    } else if (d < 0) {
        for (int j = T + d; j < T; ++j) { float v = xb[j]; pw += v; pw2 += v * v; }
    }
    float sum_w  = Sx  - pw;
    float sum_w2 = Sxx - pw2;

    float invT  = 1.0f / (float)T;
    float corr  = cr - sum_w * Sy * invT;
    float normx = sum_w2 - sum_w * sum_w * invT;
    float normy = Syy - Sy * Sy * invT;
    out[idx] = corr / sqrtf(normx * normy);
}

extern "C" void kernel_launch(void* const* d_in, const int* in_sizes, int n_in,
                              void* d_out, int out_size, void* d_ws, size_t ws_size,
                              hipStream_t stream) {
    const float* x = (const float*)d_in[0];
    const float* y = (const float*)d_in[1];
    float* out = (float*)d_out;

    const int S   = S_TOTAL;                // max_shift = 128 (fixed by setup_inputs)
    const int BC  = out_size / S;           // 8
    const int T   = in_sizes[0] / BC;       // 32768
    const int NCH = T / TY;                 // 8

    float* ws_cross = (float*)d_ws;                       // S_PAD * NCH * BC floats
    float* ws_sums  = ws_cross + (size_t)S_PAD * NCH * BC; // BC * NCH * 4 floats

    dim3 grid_c(NCH, NSG, BC);
    cross_kernel<<<grid_c, 256, 0, stream>>>(x, y, ws_cross, ws_sums, T, BC, NCH);

    int tot = S * BC;
    finalize_kernel<<<(tot + 255) / 256, 256, 0, stream>>>(x, ws_cross, ws_sums, out, T, BC, NCH);
}

// Round 3
// 80.262 us; speedup vs baseline: 1.6820x; 1.1047x over previous
//
#include <hip/hip_runtime.h>
#include <math.h>

#define MAX_SHIFT 128
#define S_TOTAL   257
#define SGB       8                    // shifts per block
#define NSB       33                   // ceil(257/8) shift-groups
#define TY        4096                 // time-chunk staged in LDS
#define VY        8                    // consecutive y elems per thread per inner iter
#define XT        (TY + 16)            // staged window (+15 reach, padded to 16)

// One block = one (shift-group, bc). Fully independent: computes its 8 cross
// sums, the global sums, and the edge corrections, then writes 8 outputs.
// Single dispatch, no workspace, no atomics.
__global__ __launch_bounds__(256) void spc_kernel(const float* __restrict__ x,
                                                  const float* __restrict__ y,
                                                  float* __restrict__ out,
                                                  int T, int BC) {
    const int sg  = blockIdx.x;            // shift group: s in [sg*8, sg*8+8)
    const int bc  = blockIdx.y;
    const int s0  = sg * SGB;
    const int d0  = s0 - MAX_SHIFT;        // shift offset of first s in group
    const int tid = threadIdx.x;
    const float* xb = x + (size_t)bc * T;
    const float* yb = y + (size_t)bc * T;
    const int NCH = T / TY;

    __shared__ __align__(16) float xs[XT];
    __shared__ float red[SGB + 4][4];      // cross[8] + {Sx,Sxx,Sy,Syy} per wave
    __shared__ float edge[SGB][2];         // per-s (pw, pw2) edge sums

    float acc[SGB];
#pragma unroll
    for (int j = 0; j < SGB; ++j) acc[j] = 0.f;
    float sx = 0.f, sxx = 0.f, sy = 0.f, syy = 0.f;

    for (int c = 0; c < NCH; ++c) {
        const int t0 = c * TY;
        const int G0 = t0 + d0;            // global x index of xs[0] (mult of 8)

        __syncthreads();                   // protect xs from previous chunk's readers
        // stage x window [G0, G0 + XT) with zero-fill outside [0, T)
        for (int ls = tid * 4; ls < XT; ls += 1024) {
            int g = G0 + ls;
            float4 v;
            if (g >= 0 && g + 3 < T) {
                v = *(const float4*)(xb + g);
            } else {
                float tmp[4];
#pragma unroll
                for (int e = 0; e < 4; ++e) {
                    int gg = g + e;
                    tmp[e] = (gg >= 0 && gg < T) ? xb[gg] : 0.f;
                }
                v = make_float4(tmp[0], tmp[1], tmp[2], tmp[3]);
            }
            *(float4*)(xs + ls) = v;
        }
        __syncthreads();

#pragma unroll
        for (int k = 0; k < TY / (256 * VY); ++k) {
            const int b = k * (256 * VY) + tid * VY;   // t-offset in chunk, mult of 8
            const int t = t0 + b;
            float yv[VY], xv[VY], xw[VY + SGB];        // 16-float x window
            *(float4*)(yv)     = *(const float4*)(yb + t);
            *(float4*)(yv + 4) = *(const float4*)(yb + t + 4);
            *(float4*)(xv)     = *(const float4*)(xb + t);
            *(float4*)(xv + 4) = *(const float4*)(xb + t + 4);
#pragma unroll
            for (int i = 0; i < (VY + SGB) / 4; ++i)
                *(float4*)(xw + 4 * i) = *(const float4*)(xs + b + 4 * i);

#pragma unroll
            for (int e = 0; e < VY; ++e) {
#pragma unroll
                for (int j = 0; j < SGB; ++j)
                    acc[j] = fmaf(xw[e + j], yv[e], acc[j]);
                sy += yv[e]; syy = fmaf(yv[e], yv[e], syy);
                sx += xv[e]; sxx = fmaf(xv[e], xv[e], sxx);
            }
        }
    }

    // ---- wave-level reductions ----
    const int lane = tid & 63, wave = tid >> 6;
#pragma unroll
    for (int j = 0; j < SGB; ++j) {
        float v = acc[j];
        for (int off = 32; off; off >>= 1) v += __shfl_down(v, off, 64);
        if (lane == 0) red[j][wave] = v;
    }
    {
        float v4[4] = {sx, sxx, sy, syy};
#pragma unroll
        for (int q = 0; q < 4; ++q) {
            float v = v4[q];
            for (int off = 32; off; off >>= 1) v += __shfl_down(v, off, 64);
            if (lane == 0) red[SGB + q][wave] = v;
        }
    }

    // ---- edge corrections: wave w handles s-locals {w, w+4} ----
    for (int sl = wave; sl < SGB; sl += 4) {
        int d = d0 + sl;
        float pw = 0.f, pw2 = 0.f;
        if (d > 0) {
            for (int j = lane; j < d; j += 64) { float v = xb[j];         pw += v; pw2 = fmaf(v, v, pw2); }
        } else if (d < 0) {
            for (int j = lane; j < -d; j += 64) { float v = xb[T + d + j]; pw += v; pw2 = fmaf(v, v, pw2); }
        }
        for (int off = 32; off; off >>= 1) {
            pw  += __shfl_down(pw,  off, 64);
            pw2 += __shfl_down(pw2, off, 64);
        }
        if (lane == 0) { edge[sl][0] = pw; edge[sl][1] = pw2; }
    }
    __syncthreads();

    // ---- finalize: 8 outputs per block ----
    if (tid < SGB) {
        int s = s0 + tid;
        if (s < S_TOTAL) {
            float cr  = red[tid][0] + red[tid][1] + red[tid][2] + red[tid][3];
            float Sx  = red[SGB + 0][0] + red[SGB + 0][1] + red[SGB + 0][2] + red[SGB + 0][3];
            float Sxx = red[SGB + 1][0] + red[SGB + 1][1] + red[SGB + 1][2] + red[SGB + 1][3];
            float Sy  = red[SGB + 2][0] + red[SGB + 2][1] + red[SGB + 2][2] + red[SGB + 2][3];
            float Syy = red[SGB + 3][0] + red[SGB + 3][1] + red[SGB + 3][2] + red[SGB + 3][3];
            float Sw  = Sx  - edge[tid][0];
            float Sw2 = Sxx - edge[tid][1];
            float invT  = 1.0f / (float)T;
            float corr  = cr  - Sw * Sy * invT;
            float normx = Sw2 - Sw * Sw * invT;
            float normy = Syy - Sy * Sy * invT;
            out[(size_t)s * BC + bc] = corr / sqrtf(normx * normy);
        }
    }
}

extern "C" void kernel_launch(void* const* d_in, const int* in_sizes, int n_in,
                              void* d_out, int out_size, void* d_ws, size_t ws_size,
                              hipStream_t stream) {
    const float* x = (const float*)d_in[0];
    const float* y = (const float*)d_in[1];
    float* out = (float*)d_out;

    const int BC = out_size / S_TOTAL;   // 8
    const int T  = in_sizes[0] / BC;     // 32768

    dim3 grid(NSB, BC);                  // 33 x 8 = 264 blocks
    spc_kernel<<<grid, 256, 0, stream>>>(x, y, out, T, BC);
}